// Round 4
// baseline (50.136 us; speedup 1.0000x reference)
//
#include <hip/hip_runtime.h>

// x: [128,8,32,32,32] f32  cw: [16,8,3,3,3] f32  cb: [16]  bias: [16]  out: [128]
// out[b] = (1/6750)*sum_{c,cells} maxpool2(conv_raw) + sum_c(cb[c]/2 + bias[c])
//
// 32x32x16 MFMA implicit GEMM: M=32 ow, N=32=(16 co x 2 od), K=16=(8 ci x 2 planes).
// Block = (b, d-half); 6-plane LDS ring walked over pd; stages each plane once.

using short8 = __attribute__((ext_vector_type(8))) short;
using f32x16 = __attribute__((ext_vector_type(16))) float;

__device__ __forceinline__ unsigned short f2bf(float f) {
  unsigned u = __float_as_uint(f);
  return (unsigned short)((u + 0x7FFFu + ((u >> 16) & 1u)) >> 16);
}

// Bp[g=(pb2*3+kh)*3+kw][lane]: 8 bf16; lane: col=l&31 (co=col&15, od=col>>4), koff=l>>5
// value j: w[co][ci=j][kd=2*pb2+koff-od][kh][kw], kd outside 0..2 -> 0
__global__ __launch_bounds__(256) void prep_w(const float* __restrict__ cw,
                                              short* __restrict__ Bp) {
  int i = threadIdx.x + blockIdx.x * 256;
  if (i >= 1152) return;
  int g = i >> 6, l = i & 63;
  int pb2 = g / 9, kh = (g / 3) % 3, kw = g % 3;
  int col = l & 31, koff = l >> 5;
  int co = col & 15, od = col >> 4;
  int kd = 2 * pb2 + koff - od;
  short8 o;
#pragma unroll
  for (int j = 0; j < 8; ++j) {
    float v = (kd >= 0 && kd <= 2) ? cw[(co * 8 + j) * 27 + kd * 9 + kh * 3 + kw] : 0.0f;
    o[j] = (short)f2bf(v);
  }
  *(short8*)(Bp + (size_t)i * 8) = o;
}

__global__ __launch_bounds__(512, 2) void conv_mfma(const float* __restrict__ x,
                                                    const short* __restrict__ Bp,
                                                    float* __restrict__ partial) {
  __shared__ __align__(16) char lds[6 * 16384];  // 6-plane ring; slab=[h32][w32][ci8] bf16
  __shared__ float red[8];
  const int blk = blockIdx.x;           // 256 blocks
  const int b = blk >> 1, dh = blk & 1; // d-half: pd 0..6 / 7..14
  const int t = threadIdx.x, lane = t & 63, wv = t >> 6;
  const int pd0 = dh ? 7 : 0;
  const int nst = dh ? 8 : 7;
  const int plane0 = 2 * pd0;
  const float* xb = x + (size_t)b * 262144;

  // ---- per-lane A addressing ----
  const int ow = lane & 31, koff = lane >> 5, hi = lane >> 5;
  int wbv[3];
#pragma unroll
  for (int kw = 0; kw < 3; ++kw) {
    int w = ow + kw; if (w > 31) w = 31;  // rows 30/31 are masked in pooling
    wbv[kw] = (w * 16) ^ (((w >> 3) & 3) << 4);
  }

  // ---- staging site decode (same (h,wq,ch) for both planes of a pair) ----
  const int sh = t >> 4, swq = (t >> 1) & 7, sch = t & 1;
  const float* gbase = xb + (size_t)(sch * 4) * 32768 + sh * 32 + swq * 4;

  auto loadSite = [&](int d, float4& v0, float4& v1, float4& v2, float4& v3) {
    const float* gp = gbase + d * 1024;
    v0 = *(const float4*)(gp);
    v1 = *(const float4*)(gp + 32768);
    v2 = *(const float4*)(gp + 65536);
    v3 = *(const float4*)(gp + 98304);
  };
  auto storeSite = [&](int d, const float4& v0, const float4& v1, const float4& v2,
                       const float4& v3) {
    char* sb = lds + (d % 6) * 16384 + sh * 512 + sch * 8;
    const float* a0 = (const float*)&v0; const float* a1 = (const float*)&v1;
    const float* a2 = (const float*)&v2; const float* a3 = (const float*)&v3;
#pragma unroll
    for (int j = 0; j < 4; ++j) {
      int w = swq * 4 + j;
      int wbyte = (w * 16) ^ (((w >> 3) & 3) << 4);
      uint2 val;
      val.x = (unsigned)f2bf(a0[j]) | ((unsigned)f2bf(a1[j]) << 16);
      val.y = (unsigned)f2bf(a2[j]) | ((unsigned)f2bf(a3[j]) << 16);
      *(uint2*)(sb + wbyte) = val;
    }
  };

  // ---- prologue: stage planes plane0..plane0+3 ----
#pragma unroll
  for (int pr = 0; pr < 4; ++pr) {
    float4 v0, v1, v2, v3;
    loadSite(plane0 + pr, v0, v1, v2, v3);
    storeSite(plane0 + pr, v0, v1, v2, v3);
  }

  // ---- B fragments (block-invariant, from L2) ----
  short8 Bw[18];
#pragma unroll
  for (int g = 0; g < 18; ++g)
    Bw[g] = *(const short8*)(Bp + ((size_t)g * 64 + lane) * 8);

  __syncthreads();

  float sum = 0.0f;
  for (int st = 0; st < nst; ++st) {
    const int pd = pd0 + st;
    const bool more = (st < nst - 1);
    const int dpair = 2 * pd + 4;  // planes staged this step (for pd+1)

    // slot bases (per-lane: +koff selects plane within K)
    int b6 = (2 * pd) % 6;
    int s0 = b6 + koff; if (s0 >= 6) s0 -= 6;
    int s1 = b6 + 2 + koff; if (s1 >= 6) s1 -= 6;
    char* lp0 = lds + s0 * 16384;
    char* lp1 = lds + s1 * 16384;

    auto chunk = [&](int q) {  // one oh-pair (rows 2q, 2q+1), 24 reads + 36 mfma
      const int oh0 = 2 * q;
      short8 fS[4][6];
#pragma unroll
      for (int j = 0; j < 4; ++j) {
        char* r0 = lp0 + (oh0 + j) * 512;
        char* r1 = lp1 + (oh0 + j) * 512;
#pragma unroll
        for (int kw = 0; kw < 3; ++kw) {
          fS[j][kw]     = *(const short8*)(r0 + wbv[kw]);
          fS[j][3 + kw] = *(const short8*)(r1 + wbv[kw]);
        }
      }
      f32x16 C[2] = {};
#pragma unroll
      for (int pb2 = 0; pb2 < 2; ++pb2)
#pragma unroll
        for (int kh = 0; kh < 3; ++kh)
#pragma unroll
          for (int kw = 0; kw < 3; ++kw) {
            const int fi = pb2 * 3 + kw;
            const int g = (pb2 * 3 + kh) * 3 + kw;
            C[0] = __builtin_amdgcn_mfma_f32_32x32x16_bf16(fS[kh][fi], Bw[g], C[0], 0, 0, 0);
            C[1] = __builtin_amdgcn_mfma_f32_32x32x16_bf16(fS[kh + 1][fi], Bw[g], C[1], 0, 0, 0);
          }
      // maxpool 2x2x2: C-rows give ow pairs; C0/C1 = oh pair; shfl_xor(16) = od pair
      float part = 0.0f;
#pragma unroll
      for (int i = 0; i < 8; ++i) {
        float v = fmaxf(fmaxf(C[0][2 * i], C[0][2 * i + 1]),
                        fmaxf(C[1][2 * i], C[1][2 * i + 1]));
        v = fmaxf(v, __shfl_xor(v, 16));
        // lane-slot (hi,i)=(1,7) is pooled-w 15 (ow 30,31): invalid; od=1 cols drop dup
        if (((lane & 31) < 16) && !(hi == 1 && i == 7)) part += v;
      }
      sum += part;
    };

    float4 v0, v1, v2, v3;
    if (more) loadSite(dpair, v0, v1, v2, v3);        // plane A issue early

    chunk(wv);                                        // q = wv (always valid, 0..7)

    if (more) {
      storeSite(dpair, v0, v1, v2, v3);
      loadSite(dpair + 1, v0, v1, v2, v3);            // plane B
    }

    if (wv < 7) chunk(wv + 8);                        // q = 8..14

    if (more) storeSite(dpair + 1, v0, v1, v2, v3);

    __syncthreads();
  }

  // ---- block reduction ----
#pragma unroll
  for (int off = 32; off; off >>= 1) sum += __shfl_down(sum, off);
  if (lane == 0) red[wv] = sum;
  __syncthreads();
  if (t == 0) {
    float s2 = 0.0f;
#pragma unroll
    for (int i = 0; i < 8; ++i) s2 += red[i];
    partial[blk] = s2;
  }
}

__global__ __launch_bounds__(128) void finalize(const float* __restrict__ partial,
                                                const float* __restrict__ cb,
                                                const float* __restrict__ bias,
                                                float* __restrict__ out) {
  int b = threadIdx.x;
  if (b >= 128) return;
  float k = 0.0f;
#pragma unroll
  for (int c = 0; c < 16; ++c) k += cb[c] * 0.5f + bias[c];
  out[b] = (partial[2 * b] + partial[2 * b + 1]) * (1.0f / 6750.0f) + k;
}

extern "C" void kernel_launch(void* const* d_in, const int* in_sizes, int n_in,
                              void* d_out, int out_size, void* d_ws, size_t ws_size,
                              hipStream_t stream) {
  const float* x    = (const float*)d_in[0];
  const float* cw   = (const float*)d_in[1];
  const float* cb   = (const float*)d_in[2];
  const float* bias = (const float*)d_in[3];
  float* out = (float*)d_out;

  short* Bp      = (short*)d_ws;                   // 1152*16 B = 18432 B
  float* partial = (float*)((char*)d_ws + 32768);  // 256 floats

  prep_w<<<5, 256, 0, stream>>>(cw, Bp);
  conv_mfma<<<256, 512, 0, stream>>>(x, Bp, partial);
  finalize<<<1, 128, 0, stream>>>(partial, cb, bias, out);
}

// Round 5
// 46.608 us; speedup vs baseline: 1.0757x; 1.0757x over previous
//
#include <hip/hip_runtime.h>

// x: [128,8,32,32,32] f32  cw: [16,8,3,3,3] f32  cb: [16]  bias: [16]  out: [128]
// out[b] = (1/6750)*sum_{c,cells} maxpool2(conv_raw) + sum_c(cb[c]/2 + bias[c])
//
// Round-3 compute structure (16x16x32 MFMA, (kd,kh)-bundled K, tg=kw, 16 ds_reads
// per 36 mfma, XOR swizzle ^((w>>3)&3)<<4), but blocks halved along h:
// block = (b, pd, h-half), 36 KiB LDS, 256 thr -> 4 blocks/CU (was 2) for
// stage/compute overlap across independent blocks.

using short8 = __attribute__((ext_vector_type(8))) short;
using f32x4  = __attribute__((ext_vector_type(4))) float;

__device__ __forceinline__ unsigned short f2bf(float f) {
  unsigned u = __float_as_uint(f);
  return (unsigned short)((u + 0x7FFFu + ((u >> 16) & 1u)) >> 16);
}

// Bp[g=kd*3+kh][lane]: 8 bf16 = w[co=lane&15][ci=j][kd][kh][kw=lane>>4]; kw==3 -> 0
__global__ __launch_bounds__(256) void prep_w(const float* __restrict__ cw,
                                              short* __restrict__ Bp) {
  int i = threadIdx.x + blockIdx.x * 256;
  if (i >= 576) return;
  int g = i >> 6, l = i & 63;
  int co = l & 15, kw = l >> 4;
  int kd = g / 3, kh = g % 3;
  short8 o;
#pragma unroll
  for (int j = 0; j < 8; ++j) {
    float v = (kw < 3) ? cw[(co * 8 + j) * 27 + kd * 9 + kh * 3 + kw] : 0.0f;
    o[j] = (short)f2bf(v);
  }
  *(short8*)(Bp + (size_t)i * 8) = o;
}

__global__ __launch_bounds__(256, 4) void conv_mfma(const float* __restrict__ x,
                                                    const short* __restrict__ Bp,
                                                    float* __restrict__ partial) {
  // LDS: [d(4)][hr(18)][w(32)][ci(8)] bf16, row=512B, plane=9216B, swizzled in w
  __shared__ __align__(16) char lds[4 * 18 * 512];  // 36864 B -> 4 blocks/CU
  __shared__ float red[4];

  const int flat = blockIdx.x;            // 3840 blocks
  const int xcd = flat & 7, idx = flat >> 3;   // 480 per XCD
  const int b   = xcd * 16 + idx / 30;    // all 30 sub-blocks of b on one XCD
  const int r30 = idx % 30;
  const int pd  = r30 >> 1, hh = r30 & 1;
  const int t = threadIdx.x, lane = t & 63, wv = t >> 6;
  const int d0  = pd * 2;
  const int hbs = hh ? 14 : 0;            // staged h rows hbs..hbs+17
  const float* xb = x + (size_t)b * 262144;

  // ---- stage 4 planes x 18 rows: f32 -> bf16, [w][ci]-packed, swizzled ----
  for (int s = t; s < 576; s += 256) {    // sites: [d(4)][hr(18)][wc(8)]
    const int d = s / 144, rem = s % 144;
    const int hr = rem >> 3, wc = rem & 7;
    const float* gp = xb + (d0 + d) * 1024 + (hbs + hr) * 32 + wc * 4;
    float4 va[8];
#pragma unroll
    for (int ci = 0; ci < 8; ++ci) va[ci] = *(const float4*)(gp + ci * 32768);
    char* rowp = lds + (d * 18 + hr) * 512;
#pragma unroll
    for (int wi = 0; wi < 4; ++wi) {
      const int w = wc * 4 + wi;
      short8 o;
#pragma unroll
      for (int ci = 0; ci < 8; ++ci) o[ci] = (short)f2bf(((const float*)&va[ci])[wi]);
      *(short8*)(rowp + ((w * 16) ^ (((w >> 3) & 3) << 4))) = o;
    }
  }

  // ---- B fragments: 9 (kd,kh) groups, block-invariant ----
  short8 Bw[9];
#pragma unroll
  for (int g = 0; g < 9; ++g)
    Bw[g] = *(const short8*)(Bp + ((size_t)g * 64 + lane) * 8);

  // ---- per-lane A w-bases (w = m + kw(tg); chunk1 +16, clamp only hits
  //      pad-tap (tg==3) or pooling-masked rows — verified in R3) ----
  const int m = lane & 15, tg = lane >> 4;
  const int w0 = m + tg;
  int w1 = m + 16 + tg; if (w1 > 31) w1 = 31;
  const int wb0 = (w0 * 16) ^ (((w0 >> 3) & 3) << 4);
  const int wb1 = (w1 * 16) ^ (((w1 >> 3) & 3) << 4);

  __syncthreads();

  // ---- tasks: half A: ph 0..7 (16 tasks); half B: ph 8..14 (14 tasks) ----
  const int ntasks = hh ? 14 : 16;
  const int rowoff = hh ? 2 : 0;  // local row = 2*ql + rowoff + (s+kh)
  float sum = 0.0f;
  for (int tid = wv; tid < ntasks; tid += 4) {
    const int ql = tid >> 1, c = tid & 1;
    const int base = (c ? wb1 : wb0) + (2 * ql + rowoff) * 512;
    f32x4 cc[2][2] = {};  // [od][s], 16 ow x 16 co
#pragma unroll
    for (int p = 0; p < 4; ++p) {
#pragma unroll
      for (int rr = 0; rr < 4; ++rr) {
        const short8 a = *(const short8*)(lds + base + p * 9216 + rr * 512);
        if (p < 3 && rr < 3)
          cc[0][0] = __builtin_amdgcn_mfma_f32_16x16x32_bf16(a, Bw[p * 3 + rr], cc[0][0], 0, 0, 0);
        if (p < 3 && rr > 0)
          cc[0][1] = __builtin_amdgcn_mfma_f32_16x16x32_bf16(a, Bw[p * 3 + rr - 1], cc[0][1], 0, 0, 0);
        if (p > 0 && rr < 3)
          cc[1][0] = __builtin_amdgcn_mfma_f32_16x16x32_bf16(a, Bw[(p - 1) * 3 + rr], cc[1][0], 0, 0, 0);
        if (p > 0 && rr > 0)
          cc[1][1] = __builtin_amdgcn_mfma_f32_16x16x32_bf16(a, Bw[(p - 1) * 3 + rr - 1], cc[1][1], 0, 0, 0);
      }
    }
    // maxpool 2x2x2: C rows = ow pairs; mask ow 30/31 of chunk1
#pragma unroll
    for (int p2 = 0; p2 < 2; ++p2) {
      float v = fmaxf(fmaxf(fmaxf(cc[0][0][2 * p2], cc[0][0][2 * p2 + 1]),
                            fmaxf(cc[0][1][2 * p2], cc[0][1][2 * p2 + 1])),
                      fmaxf(fmaxf(cc[1][0][2 * p2], cc[1][0][2 * p2 + 1]),
                            fmaxf(cc[1][1][2 * p2], cc[1][1][2 * p2 + 1])));
      const bool inval = (c == 1) && (tg == 3) && (p2 == 1);
      sum += inval ? 0.0f : v;
    }
  }

  // ---- block reduction ----
#pragma unroll
  for (int off = 32; off; off >>= 1) sum += __shfl_down(sum, off);
  if (lane == 0) red[wv] = sum;
  __syncthreads();
  if (t == 0)
    partial[b * 30 + pd * 2 + hh] = red[0] + red[1] + red[2] + red[3];
}

__global__ __launch_bounds__(64) void finalize(const float* __restrict__ partial,
                                               const float* __restrict__ cb,
                                               const float* __restrict__ bias,
                                               float* __restrict__ out) {
  const int b = blockIdx.x, t = threadIdx.x;
  float s = (t < 30) ? partial[b * 30 + t] : 0.0f;
#pragma unroll
  for (int off = 32; off; off >>= 1) s += __shfl_down(s, off);
  if (t == 0) {
    float k = 0.0f;
#pragma unroll
    for (int c = 0; c < 16; ++c) k += cb[c] * 0.5f + bias[c];
    out[b] = s * (1.0f / 6750.0f) + k;
  }
}

extern "C" void kernel_launch(void* const* d_in, const int* in_sizes, int n_in,
                              void* d_out, int out_size, void* d_ws, size_t ws_size,
                              hipStream_t stream) {
  const float* x    = (const float*)d_in[0];
  const float* cw   = (const float*)d_in[1];
  const float* cb   = (const float*)d_in[2];
  const float* bias = (const float*)d_in[3];
  float* out = (float*)d_out;

  short* Bp      = (short*)d_ws;                   // 576*16 B = 9216 B
  float* partial = (float*)((char*)d_ws + 32768);  // 3840 floats

  prep_w<<<3, 256, 0, stream>>>(cw, Bp);
  conv_mfma<<<3840, 256, 0, stream>>>(x, Bp, partial);
  finalize<<<128, 64, 0, stream>>>(partial, cb, bias, out);
}